// Round 20
// baseline (230.266 us; speedup 1.0000x reference)
//
#include <hip/hip_runtime.h>

typedef __attribute__((ext_vector_type(8))) __bf16 bf16x8;
typedef __attribute__((ext_vector_type(4))) float f32x4;
typedef __attribute__((ext_vector_type(16))) float f32x16;
typedef unsigned short u16;

// Problem constants
#define TSEQ   2048
#define NB     4
#define NHEAD  16
#define HDIM   64
#define CMODEL 1024
#define MTOK   (NB*TSEQ)          // 8192 tokens

__device__ __forceinline__ u16 f2bf(float x){
  unsigned u = __float_as_uint(x);
  u += 0x7fffu + ((u >> 16) & 1u);          // RNE (no NaN inputs here)
  return (u16)(u >> 16);
}

// pack 2 f32 -> u32 of 2 bf16 (lo in low 16), RNE
__device__ __forceinline__ unsigned cvtpk(float lo, float hi){
  unsigned r;
  asm("v_cvt_pk_bf16_f32 %0, %1, %2" : "=v"(r) : "v"(lo), "v"(hi));
  return r;
}
// v_permlane32_swap: a.lanes[32:63] <-> b.lanes[0:31]
__device__ __forceinline__ void plswap(unsigned &a, unsigned &b){
  asm volatile("v_permlane32_swap_b32 %0, %1" : "+v"(a), "+v"(b));
}

// async global->LDS, 16B per lane. lds_base must be wave-uniform (affine in
// lane with 16B slope); HW writes lane i at base + i*16.
__device__ __forceinline__ void async16(const void* g, const u16* lds_base){
  __builtin_amdgcn_global_load_lds(
      (const __attribute__((address_space(1))) unsigned*)(uintptr_t)g,
      (__attribute__((address_space(3))) unsigned*)(unsigned)(uintptr_t)lds_base,
      16, 0, 0);
}

// ---------------------------------------------------------------------------
// prep kernels
// ---------------------------------------------------------------------------
__global__ void cast_bf16_kernel(const float* __restrict__ src, u16* __restrict__ dst, int n4){
  int i = blockIdx.x * blockDim.x + threadIdx.x;
  int stride = gridDim.x * blockDim.x;
  for (; i < n4; i += stride){
    float4 v = ((const float4*)src)[i];
    ((ushort4*)dst)[i] = make_ushort4(f2bf(v.x), f2bf(v.y), f2bf(v.z), f2bf(v.w));
  }
}

__global__ void cast4_bf16_kernel(const float* __restrict__ s0, const float* __restrict__ s1,
                                  const float* __restrict__ s2, const float* __restrict__ s3,
                                  u16* __restrict__ d0, u16* __restrict__ d1,
                                  u16* __restrict__ d2, u16* __restrict__ d3, int n4){
  int which = blockIdx.y;
  const float* s = (which==0)?s0:(which==1)?s1:(which==2)?s2:s3;
  u16* d        = (which==0)?d0:(which==1)?d1:(which==2)?d2:d3;
  int i = blockIdx.x * blockDim.x + threadIdx.x;
  int stride = gridDim.x * blockDim.x;
  for (; i < n4; i += stride){
    float4 v = ((const float4*)s)[i];
    ((ushort4*)d)[i] = make_ushort4(f2bf(v.x), f2bf(v.y), f2bf(v.z), f2bf(v.w));
  }
}

__global__ void rope_table_kernel(float2* __restrict__ rope){
  int i = blockIdx.x * blockDim.x + threadIdx.x;       // T * HDIM/2 = 2048*32
  if (i >= TSEQ * (HDIM/2)) return;
  int t = i >> 5, j = i & 31;
  float theta = exp2f(-(float)j * (13.287712379549449f / 32.f));
  float ang = (float)t * theta;
  rope[i] = make_float2(cosf(ang), sinf(ang));
}

// ---------------------------------------------------------------------------
// 128x128 tile GEMM, BK=64, double-staged LDS (verified; used by proj).
// ---------------------------------------------------------------------------
__device__ __forceinline__ void gemm128_mainloop(
    const u16* __restrict__ A, const u16* __restrict__ B,
    int m0, int n0, int K, u16* sA, u16* sB, f32x4 acc[4][4])
{
  const int tid = threadIdx.x;
  const int w = tid >> 6, lane = tid & 63;
  const int ln = lane & 15, g = lane >> 4;
  const int wm = w >> 1, wn = w & 1;

  const f32x4 zero = {0.f, 0.f, 0.f, 0.f};
#pragma unroll
  for (int mt = 0; mt < 4; ++mt)
#pragma unroll
    for (int nt = 0; nt < 4; ++nt) acc[mt][nt] = zero;

  for (int k0 = 0; k0 < K; k0 += 64){
    __syncthreads();                       // previous tile fully consumed
#pragma unroll
    for (int i = 0; i < 4; ++i){
      int c = i*256 + tid;                 // chunk id 0..1023
      int r = c >> 3, sl = c & 7;
      int ks = sl ^ (r & 7);               // pre-swizzled source k-chunk
      async16(A + (size_t)(m0 + r)*K + k0 + ks*8, sA + (size_t)(i*256 + w*64)*8);
      async16(B + (size_t)(n0 + r)*K + k0 + ks*8, sB + (size_t)(i*256 + w*64)*8);
    }
    __syncthreads();                       // drains vmcnt -> LDS ready

#pragma unroll
    for (int kk = 0; kk < 2; ++kk){
      bf16x8 af[4], bfr[4];
#pragma unroll
      for (int mt = 0; mt < 4; ++mt){
        int row = wm*64 + mt*16 + ln;
        int sl = (kk*4 + g) ^ (row & 7);
        af[mt] = *(const bf16x8*)&sA[row*64 + sl*8];
      }
#pragma unroll
      for (int nt = 0; nt < 4; ++nt){
        int row = wn*64 + nt*16 + ln;
        int sl = (kk*4 + g) ^ (row & 7);
        bfr[nt] = *(const bf16x8*)&sB[row*64 + sl*8];
      }
      __builtin_amdgcn_s_setprio(1);
#pragma unroll
      for (int mt = 0; mt < 4; ++mt)
#pragma unroll
        for (int nt = 0; nt < 4; ++nt)
          acc[mt][nt] = __builtin_amdgcn_mfma_f32_16x16x32_bf16(af[mt], bfr[nt], acc[mt][nt], 0, 0, 0);
      __builtin_amdgcn_s_setprio(0);
    }
  }
}

// ---------------------------------------------------------------------------
// QKV projection, 128M x 256N tile (BK=64): 64 MFMA per barrier-pair.
// XCD cohort: 8 my-panels per XCD; rem -> (z, mx) sweeps 12 B-panels.
// Epilogue: bias + RoPE(Q,K) + head-split; V transposed. Q pre-scaled.
// ---------------------------------------------------------------------------
#define SCQ 0.18033688011112042f   // 0.125 * log2(e)

__global__ __launch_bounds__(256) void gemm_qkv_kernel(
    const u16* __restrict__ xb,
    const u16* __restrict__ wqb, const u16* __restrict__ wkb, const u16* __restrict__ wvb,
    const float* __restrict__ bq, const float* __restrict__ bk, const float* __restrict__ bv,
    const float2* __restrict__ rope,
    u16* __restrict__ Qh, u16* __restrict__ Kh, u16* __restrict__ Vt)
{
  __shared__ u16 sA[128*64];   // 16 KB
  __shared__ u16 sB[256*64];   // 32 KB

  // bid 0..767 -> xcd cohort decode (8 my-panels per XCD)
  const int bid = blockIdx.x;
  const int xcd = bid & 7, gg = bid >> 3;      // gg: 0..95
  const int slot = xcd * 96 + gg;
  const int my   = slot / 12;                  // A-panel 0..63
  const int rem  = slot % 12;
  const int z    = rem >> 2;                   // weight 0..2
  const int mx   = rem & 3;                    // 256-wide n-tile 0..3

  const u16*  W    = (z == 0) ? wqb : (z == 1) ? wkb : wvb;
  const float* bias = (z == 0) ? bq  : (z == 1) ? bk  : bv;
  const int m0 = my * 128, n0 = mx * 256;

  const int tid = threadIdx.x, w = tid >> 6, lane = tid & 63;
  const int ln = lane & 15, g = lane >> 4;
  const int wm = w >> 1, wn = w & 1;

  // staging bases: chunk c -> row c>>3, slot c&7, src k-chunk (c&7)^((c>>3)&7).
  // For c = i*256+tid: row = i*32 + (tid>>3); (row&7) = (tid>>3)&7 -> ks const in i.
  const int tr = tid >> 3;
  const int ks = (tid & 7) ^ (tr & 7);
  const unsigned aso = (unsigned)(m0 + tr) * CMODEL + ks*8;   // + i*32*CMODEL
  const unsigned bso = (unsigned)(n0 + tr) * CMODEL + ks*8;   // + j*32*CMODEL
  const unsigned dstb = (unsigned)tid * 8;                    // + {i,j}*2048

  f32x4 acc[4][8];
  const f32x4 zero = {0.f,0.f,0.f,0.f};
#pragma unroll
  for (int mt = 0; mt < 4; ++mt)
#pragma unroll
    for (int nt = 0; nt < 8; ++nt) acc[mt][nt] = zero;

  for (int k0 = 0; k0 < CMODEL; k0 += 64){
    __syncthreads();
#pragma unroll
    for (int i = 0; i < 4; ++i)
      async16(xb + aso + (unsigned)i*32*CMODEL + k0, sA + (unsigned)i*2048 + dstb);
#pragma unroll
    for (int j = 0; j < 8; ++j)
      async16(W + bso + (unsigned)j*32*CMODEL + k0, sB + (unsigned)j*2048 + dstb);
    __syncthreads();

#pragma unroll
    for (int kk = 0; kk < 2; ++kk){
      const unsigned slk = (unsigned)((kk*4 + g) ^ (ln & 7)) * 8;
      bf16x8 af[4], bf[8];
#pragma unroll
      for (int mt = 0; mt < 4; ++mt)
        af[mt] = *(const bf16x8*)&sA[(unsigned)(wm*64 + mt*16 + ln)*64 + slk];
#pragma unroll
      for (int nt = 0; nt < 8; ++nt)
        bf[nt] = *(const bf16x8*)&sB[(unsigned)(wn*128 + nt*16 + ln)*64 + slk];
      __builtin_amdgcn_s_setprio(1);
#pragma unroll
      for (int mt = 0; mt < 4; ++mt)
#pragma unroll
        for (int nt = 0; nt < 8; ++nt)
          acc[mt][nt] = __builtin_amdgcn_mfma_f32_16x16x32_bf16(af[mt], bf[nt], acc[mt][nt], 0, 0, 0);
      __builtin_amdgcn_s_setprio(0);
    }
  }

#pragma unroll
  for (int mt = 0; mt < 4; ++mt){
#pragma unroll
    for (int nt = 0; nt < 8; ++nt){
      int o  = n0 + wn*128 + nt*16 + ln;   // output feature 0..1023
      float bb = bias[o];
      int h  = o >> 6;
      int dd = o & 63;
      if (z < 2){
        int j = dd >> 1;
        u16* dst = (z == 0) ? Qh : Kh;
        float qs = (z == 0) ? SCQ : 1.0f;
#pragma unroll
        for (int rr = 0; rr < 4; ++rr){
          int t  = m0 + wm*64 + mt*16 + g*4 + rr;   // global token
          int b  = t >> 11, tt = t & (TSEQ-1);
          float v  = acc[mt][nt][rr] + bb;
          float pv = __shfl_xor(v, 1);              // rope partner (o^1), same row
          float2 cs = rope[tt*32 + j];
          float out = ((o & 1) == 0) ? (v*cs.x - pv*cs.y) : (pv*cs.y + v*cs.x);
          dst[(size_t)((b*NHEAD + h)*TSEQ + tt)*HDIM + dd] = f2bf(out * qs);
        }
      } else {
        int t0 = m0 + wm*64 + mt*16 + g*4;
        int b  = t0 >> 11, tt0 = t0 & (TSEQ-1);
        u16 pk[4];
#pragma unroll
        for (int rr = 0; rr < 4; ++rr) pk[rr] = f2bf(acc[mt][nt][rr] + bb);
        *(ushort4*)&Vt[(size_t)((b*NHEAD + h)*HDIM + dd)*TSEQ + tt0] =
            make_ushort4(pk[0], pk[1], pk[2], pk[3]);
      }
    }
  }
}

// ---------------------------------------------------------------------------
// Flash attention v15 (round-19 best) — unchanged.
// ---------------------------------------------------------------------------
__global__ __launch_bounds__(512, 4) void attn_kernel(
    const u16* __restrict__ Qh, const u16* __restrict__ Kh,
    const u16* __restrict__ Vt, u16* __restrict__ yb)
{
  __shared__ u16 sK[3][64*64];
  __shared__ u16 sV[3][64*64];

  const int tid = threadIdx.x, w = tid >> 6, lane = tid & 63;
  const int ln = lane & 31, hi = lane >> 5;

  const int bid = blockIdx.x;                  // 0..511
  const int q8  = bid >> 6;                    // 0..7
  const int s   = (q8 < 4) ? (7 - q8) : (q8 - 4);  // balanced pairing
  const int bh  = (bid & 7) * 8 + ((bid >> 3) & 7);
  const int b   = bh >> 4, h = bh & (NHEAD-1);

  const u16* Qbase = Qh + (size_t)bh * TSEQ * HDIM;
  const u16* Kbase = Kh + (size_t)bh * TSEQ * HDIM;
  const u16* Vbase = Vt + (size_t)bh * HDIM * TSEQ;

  // staging: thread stages chunk tid of K tile and of V tile (8KB each)
  const int cr = tid >> 3, cs = tid & 7;
  const u16* kp = Kbase + (size_t)cr*HDIM + ((cs ^ (cr&7))<<3);
  const u16* vp = Vbase + (size_t)cr*TSEQ + ((cs ^ (cr&7))<<3);
  const unsigned dstw = (unsigned)(w*64)*8;    // wave-uniform LDS base (u16)

  // frag read offsets (u16 units), rows are 64-u16 wide
  const int swz = ln & 7;
  unsigned offd[4];
#pragma unroll
  for (int d = 0; d < 4; ++d) offd[d] = ((unsigned)((2*d + hi) ^ swz)) * 8;
  const unsigned rowl = (unsigned)ln * 64;
  const unsigned rowh = rowl + 32*64;

  const f32x16 zero16 = {0,0,0,0,0,0,0,0,0,0,0,0,0,0,0,0};
  const int wodd = w & 1;

  const int r0  = s*256 + w*32;                // wave's first q-row
  const int jtb = 4*s + 3;                     // supertile's last kv-tile
  const int jtw = 4*s + (w >> 1);              // wave's diagonal kv-tile

  // Q fragments
  bf16x8 qf[4];
#pragma unroll
  for (int ds = 0; ds < 4; ++ds)
    qf[ds] = *(const bf16x8*)&Qbase[(size_t)(r0 + ln)*HDIM + ds*16 + hi*8];

  f32x16 yacc0 = zero16, yacc1 = zero16;
  float m2 = -1e30f, lp = 0.f;

  // prologue: stage tiles 0,1 -> bufs 0,1  (jtb >= 3 always)
  async16(kp,                   sK[0] + dstw);
  async16(vp,                   sV[0] + dstw);
  async16(kp + (size_t)64*HDIM, sK[1] + dstw);
  async16(vp + 64,              sV[1] + dstw);
  asm volatile("s_waitcnt vmcnt(2)" ::: "memory");
  asm volatile("s_barrier" ::: "memory");

#pragma unroll 1
  for (int jt = 0; jt <= jtb; ++jt){
    // stage jt+2 into buf (jt+2)%3
    const bool st2 = (jt + 2 <= jtb);
    if (st2){
      const int nb = (jt + 2) % 3;
      async16(kp + (size_t)(jt+2)*64*HDIM, sK[nb] + dstw);
      async16(vp + (size_t)(jt+2)*64,      sV[nb] + dstw);
    }

    if (jt <= jtw){
      const int cb = jt % 3;
      const u16* sKb = sK[cb];
      const u16* sVb = sV[cb];
      const bool full1 = (jt < jtw) || wodd;

      // ---- QK^T (swapped): p0 = kv rows 0..31, p1 = 32..63 ----
      f32x16 p0 = zero16, p1 = zero16;
      __builtin_amdgcn_s_setprio(1);
#pragma unroll
      for (int ds = 0; ds < 4; ++ds){
        bf16x8 k0 = *(const bf16x8*)&sKb[rowl + offd[ds]];
        p0 = __builtin_amdgcn_mfma_f32_32x32x16_bf16(k0, qf[ds], p0, 0, 0, 0);
      }
      if (full1){
#pragma unroll
        for (int ds = 0; ds < 4; ++ds){
          bf16x8 k1 = *(const bf16x8*)&sKb[rowh + offd[ds]];
          p1 = __builtin_amdgcn_mfma_f32_32x32x16_bf16(k1, qf[ds], p1, 0, 0, 0);
        }
      }
      __builtin_amdgcn_s_setprio(0);

      // ---- causal mask on the wave's diag tile ----
      if (jt == jtw){
#pragma unroll
        for (int r = 0; r < 16; ++r){
          int k0r = (r&3) + 8*(r>>2) + 4*hi;
          bool cut = k0r > ln;
          if (!wodd){ if (cut) p0[r] = -1e30f; }
          else      { if (cut) p1[r] = -1e30f; }
        }
      }

      // ---- lane-local row max ----
      float lm = p0[0];
#pragma unroll
      for (int r = 1; r < 16; ++r) lm = fmaxf(lm, p0[r]);
      if (full1){
#pragma unroll
        for (int r = 0; r < 16; ++r) lm = fmaxf(lm, p1[r]);
      }

      // defer-max
      if (__any(lm - m2 > 8.0f)){
        float lmp = __shfl_xor(lm, 32);
        float mn  = fmaxf(m2, fmaxf(lm, lmp));
        float scl = exp2f(m2 - mn);
        m2 = mn;
        lp *= scl;
#pragma unroll
        for (int r = 0; r < 16; ++r){
          float sr = __shfl(scl, (r&3) + 8*(r>>2) + 4*hi);
          yacc0[r] *= sr; yacc1[r] *= sr;
        }
      }

      // ---- exp + per-lane partial sum ----
      float ts = 0.f;
#pragma unroll
      for (int r = 0; r < 16; ++r){ p0[r] = exp2f(p0[r] - m2); ts += p0[r]; }
      if (full1){
#pragma unroll
        for (int r = 0; r < 16; ++r){ p1[r] = exp2f(p1[r] - m2); ts += p1[r]; }
      }
      lp += ts;

      // ---- pack P into PV A-fragments ----
      bf16x8 pa[4];
      {
        union { unsigned u[4]; bf16x8 v; } f0, f1;
        unsigned A0 = cvtpk(p0[0], p0[1]),  B0 = cvtpk(p0[2], p0[3]);
        unsigned A1 = cvtpk(p0[4], p0[5]),  B1 = cvtpk(p0[6], p0[7]);
        plswap(A0, A1); plswap(B0, B1);
        f0.u[0]=A0; f0.u[1]=B0; f0.u[2]=A1; f0.u[3]=B1;  pa[0]=f0.v;
        unsigned A2 = cvtpk(p0[8], p0[9]),  B2 = cvtpk(p0[10], p0[11]);
        unsigned A3 = cvtpk(p0[12], p0[13]),B3 = cvtpk(p0[14], p0[15]);
        plswap(A2, A3); plswap(B2, B3);
        f1.u[0]=A2; f1.u[1]=B2; f1.u[2]=A3; f1.u[3]=B3;  pa[1]=f1.v;
      }
      if (full1){
        union { unsigned u[4]; bf16x8 v; } f2, f3;
        unsigned A4 = cvtpk(p1[0], p1[1]),  B4 = cvtpk(p1[2], p1[3]);
        unsigned A5 = cvtpk(p1[4], p1[5]),  B5 = cvtpk(p1[6], p1[7]);
        plswap(A4, A5); plswap(B4, B5);
        f2.u[0]=A4; f2.u[1]=B4; f2.u[2]=A5; f2.u[3]=B5;  pa[2]=f2.v;
        unsigned A6 = cvtpk(p1[8], p1[9]),  B6 = cvtpk(p1[10], p1[11]);
        unsigned A7 = cvtpk(p1[12], p1[13]),B7 = cvtpk(p1[14], p1[15]);
        plswap(A6, A7); plswap(B6, B7);
        f3.u[0]=A6; f3.u[1]=B6; f3.u[2]=A7; f3.u[3]=B7;  pa[3]=f3.v;
      }

      // ---- PV ----
      __builtin_amdgcn_s_setprio(1);
#pragma unroll
      for (int st = 0; st < 2; ++st){
        bf16x8 v0 = *(const bf16x8*)&sVb[rowl + offd[st]];
        bf16x8 v1 = *(const bf16x8*)&sVb[rowh + offd[st]];
        yacc0 = __builtin_amdgcn_mfma_f32_32x32x16_bf16(pa[st], v0, yacc0, 0, 0, 0);
        yacc1 = __builtin_amdgcn_mfma_f32_32x32x16_bf16(pa[st], v1, yacc1, 0, 0, 0);
      }
      if (full1){
#pragma unroll
        for (int st = 2; st < 4; ++st){
          bf16x8 v0 = *(const bf16x8*)&sVb[rowl + offd[st]];
          bf16x8 v1 = *(const bf16x8*)&sVb[rowh + offd[st]];
          yacc0 = __builtin_amdgcn_mfma_f32_32x32x16_bf16(pa[st], v0, yacc0, 0, 0, 0);
          yacc1 = __builtin_amdgcn_mfma_f32_32x32x16_bf16(pa[st], v1, yacc1, 0, 0, 0);
        }
      }
      __builtin_amdgcn_s_setprio(0);
    }

    // ledger: ensure stage(jt+1) landed before next iter; never 0 until tail
    if (st2) asm volatile("s_waitcnt vmcnt(2)" ::: "memory");
    else     asm volatile("s_waitcnt vmcnt(0)" ::: "memory");
    asm volatile("s_barrier" ::: "memory");
  }

  // ---- epilogue: full row sum, divide, write [token][C] bf16 ----
  float lpf = lp + __shfl_xor(lp, 32);
  float inv = 1.0f / lpf;
#pragma unroll
  for (int r = 0; r < 16; ++r){
    int q = (r&3) + 8*(r>>2) + 4*hi;
    float ir = __shfl(inv, q);
    int tt = r0 + q;
    size_t rowoff = (size_t)(b*TSEQ + tt)*CMODEL + h*HDIM;
    yb[rowoff + ln]      = f2bf(yacc0[r] * ir);
    yb[rowoff + 32 + ln] = f2bf(yacc1[r] * ir);
  }
}

// ---------------------------------------------------------------------------
// output projection (128x128 BK=64), XCD-cohort remap (8 blocks per A-panel).
// ---------------------------------------------------------------------------
__global__ __launch_bounds__(256) void gemm_proj_kernel(
    const u16* __restrict__ yb, const u16* __restrict__ wpb,
    const float* __restrict__ bp, float* __restrict__ out)
{
  __shared__ u16 sA[128*64];
  __shared__ u16 sB[128*64];

  const int bid = blockIdx.x;                  // 0..511
  const int xcd = bid & 7, gg = bid >> 3;      // gg: 0..63
  const int slot = xcd * 64 + gg;
  const int my   = slot >> 3;                  // A-panel 0..63
  const int mx   = slot & 7;                   // n-tile 0..7
  const int m0 = my * 128, n0 = mx * 128;

  f32x4 acc[4][4];
  gemm128_mainloop(yb, wpb, m0, n0, CMODEL, sA, sB, acc);

  const int tid = threadIdx.x, w = tid >> 6, lane = tid & 63;
  const int ln = lane & 15, g = lane >> 4;
  const int wm = w >> 1, wn = w & 1;
#pragma unroll
  for (int mt = 0; mt < 4; ++mt)
#pragma unroll
    for (int nt = 0; nt < 4; ++nt){
      int o = n0 + wn*64 + nt*16 + ln;
      float bb = bp[o];
#pragma unroll
      for (int rr = 0; rr < 4; ++rr){
        int t = m0 + wm*64 + mt*16 + g*4 + rr;
        out[(size_t)t*CMODEL + o] = acc[mt][nt][rr] + bb;
      }
    }
}

// ---------------------------------------------------------------------------
extern "C" void kernel_launch(void* const* d_in, const int* in_sizes, int n_in,
                              void* d_out, int out_size, void* d_ws, size_t ws_size,
                              hipStream_t stream)
{
  const float* x  = (const float*)d_in[0];
  const float* wq = (const float*)d_in[1];
  const float* bq = (const float*)d_in[2];
  const float* wk = (const float*)d_in[3];
  const float* bk = (const float*)d_in[4];
  const float* wv = (const float*)d_in[5];
  const float* bv = (const float*)d_in[6];
  const float* wp = (const float*)d_in[7];
  const float* bp = (const float*)d_in[8];

  char* ws = (char*)d_ws;
  u16*    xb   = (u16*)   (ws + 0);           // 16 MiB
  u16*    wqb  = (u16*)   (ws + 16777216);    // 2 MiB
  u16*    wkb  = (u16*)   (ws + 18874368);
  u16*    wvb  = (u16*)   (ws + 20971520);
  u16*    wpb  = (u16*)   (ws + 23068672);
  float2* rope = (float2*)(ws + 25165824);    // 512 KiB
  u16*    Qh   = (u16*)   (ws + 25690112);    // 16 MiB  [bh][t][d]
  u16*    Kh   = (u16*)   (ws + 42467328);    // 16 MiB  [bh][t][d]
  u16*    Vt   = (u16*)   (ws + 59244544);    // 16 MiB  [bh][d][t]
  u16*    yb   = (u16*)   (ws + 76021760);    // 16 MiB  [token][C]

  cast_bf16_kernel<<<2048, 256, 0, stream>>>(x,  xb,  MTOK*CMODEL/4);
  cast4_bf16_kernel<<<dim3(256, 4), 256, 0, stream>>>(wq, wk, wv, wp, wqb, wkb, wvb, wpb,
                                                      CMODEL*CMODEL/4);
  rope_table_kernel<<<(TSEQ*(HDIM/2) + 255)/256, 256, 0, stream>>>(rope);

  gemm_qkv_kernel<<<dim3(768), 256, 0, stream>>>(
      xb, wqb, wkb, wvb, bq, bk, bv, rope, Qh, Kh, Vt);

  attn_kernel<<<dim3(512), 512, 0, stream>>>(Qh, Kh, Vt, yb);

  gemm_proj_kernel<<<dim3(512), 256, 0, stream>>>(yb, wpb, bp, (float*)d_out);
}

// Round 21
// 188.205 us; speedup vs baseline: 1.2235x; 1.2235x over previous
//
#include <hip/hip_runtime.h>

typedef __attribute__((ext_vector_type(8))) __bf16 bf16x8;
typedef __attribute__((ext_vector_type(4))) float f32x4;
typedef __attribute__((ext_vector_type(16))) float f32x16;
typedef unsigned short u16;

// Problem constants
#define TSEQ   2048
#define NB     4
#define NHEAD  16
#define HDIM   64
#define CMODEL 1024
#define MTOK   (NB*TSEQ)          // 8192 tokens

__device__ __forceinline__ u16 f2bf(float x){
  unsigned u = __float_as_uint(x);
  u += 0x7fffu + ((u >> 16) & 1u);          // RNE (no NaN inputs here)
  return (u16)(u >> 16);
}

// pack 2 f32 -> u32 of 2 bf16 (lo in low 16), RNE
__device__ __forceinline__ unsigned cvtpk(float lo, float hi){
  unsigned r;
  asm("v_cvt_pk_bf16_f32 %0, %1, %2" : "=v"(r) : "v"(lo), "v"(hi));
  return r;
}
// v_permlane32_swap: a.lanes[32:63] <-> b.lanes[0:31]
__device__ __forceinline__ void plswap(unsigned &a, unsigned &b){
  asm volatile("v_permlane32_swap_b32 %0, %1" : "+v"(a), "+v"(b));
}

// async global->LDS, 16B per lane. lds_base must be wave-uniform (affine in
// lane with 16B slope); HW writes lane i at base + i*16.
__device__ __forceinline__ void async16(const void* g, const u16* lds_base){
  __builtin_amdgcn_global_load_lds(
      (const __attribute__((address_space(1))) unsigned*)(uintptr_t)g,
      (__attribute__((address_space(3))) unsigned*)(unsigned)(uintptr_t)lds_base,
      16, 0, 0);
}

// ---------------------------------------------------------------------------
// prep kernels
// ---------------------------------------------------------------------------
__global__ void cast_bf16_kernel(const float* __restrict__ src, u16* __restrict__ dst, int n4){
  int i = blockIdx.x * blockDim.x + threadIdx.x;
  int stride = gridDim.x * blockDim.x;
  for (; i < n4; i += stride){
    float4 v = ((const float4*)src)[i];
    ((ushort4*)dst)[i] = make_ushort4(f2bf(v.x), f2bf(v.y), f2bf(v.z), f2bf(v.w));
  }
}

__global__ void cast4_bf16_kernel(const float* __restrict__ s0, const float* __restrict__ s1,
                                  const float* __restrict__ s2, const float* __restrict__ s3,
                                  u16* __restrict__ d0, u16* __restrict__ d1,
                                  u16* __restrict__ d2, u16* __restrict__ d3, int n4){
  int which = blockIdx.y;
  const float* s = (which==0)?s0:(which==1)?s1:(which==2)?s2:s3;
  u16* d        = (which==0)?d0:(which==1)?d1:(which==2)?d2:d3;
  int i = blockIdx.x * blockDim.x + threadIdx.x;
  int stride = gridDim.x * blockDim.x;
  for (; i < n4; i += stride){
    float4 v = ((const float4*)s)[i];
    ((ushort4*)d)[i] = make_ushort4(f2bf(v.x), f2bf(v.y), f2bf(v.z), f2bf(v.w));
  }
}

__global__ void rope_table_kernel(float2* __restrict__ rope){
  int i = blockIdx.x * blockDim.x + threadIdx.x;       // T * HDIM/2 = 2048*32
  if (i >= TSEQ * (HDIM/2)) return;
  int t = i >> 5, j = i & 31;
  float theta = exp2f(-(float)j * (13.287712379549449f / 32.f));
  float ang = (float)t * theta;
  rope[i] = make_float2(cosf(ang), sinf(ang));
}

// ---------------------------------------------------------------------------
// 128x128 tile GEMM, BK=64, double-staged LDS (32KB -> ~4 blocks/CU).
// ---------------------------------------------------------------------------
__device__ __forceinline__ void gemm128_mainloop(
    const u16* __restrict__ A, const u16* __restrict__ B,
    int m0, int n0, int K, u16* sA, u16* sB, f32x4 acc[4][4])
{
  const int tid = threadIdx.x;
  const int w = tid >> 6, lane = tid & 63;
  const int ln = lane & 15, g = lane >> 4;
  const int wm = w >> 1, wn = w & 1;

  const f32x4 zero = {0.f, 0.f, 0.f, 0.f};
#pragma unroll
  for (int mt = 0; mt < 4; ++mt)
#pragma unroll
    for (int nt = 0; nt < 4; ++nt) acc[mt][nt] = zero;

  for (int k0 = 0; k0 < K; k0 += 64){
    __syncthreads();                       // previous tile fully consumed
#pragma unroll
    for (int i = 0; i < 4; ++i){
      int c = i*256 + tid;                 // chunk id 0..1023
      int r = c >> 3, sl = c & 7;
      int ks = sl ^ (r & 7);               // pre-swizzled source k-chunk
      async16(A + (size_t)(m0 + r)*K + k0 + ks*8, sA + (size_t)(i*256 + w*64)*8);
      async16(B + (size_t)(n0 + r)*K + k0 + ks*8, sB + (size_t)(i*256 + w*64)*8);
    }
    __syncthreads();                       // drains vmcnt -> LDS ready

#pragma unroll
    for (int kk = 0; kk < 2; ++kk){
      bf16x8 af[4], bfr[4];
#pragma unroll
      for (int mt = 0; mt < 4; ++mt){
        int row = wm*64 + mt*16 + ln;
        int sl = (kk*4 + g) ^ (row & 7);
        af[mt] = *(const bf16x8*)&sA[row*64 + sl*8];
      }
#pragma unroll
      for (int nt = 0; nt < 4; ++nt){
        int row = wn*64 + nt*16 + ln;
        int sl = (kk*4 + g) ^ (row & 7);
        bfr[nt] = *(const bf16x8*)&sB[row*64 + sl*8];
      }
      __builtin_amdgcn_s_setprio(1);
#pragma unroll
      for (int mt = 0; mt < 4; ++mt)
#pragma unroll
        for (int nt = 0; nt < 4; ++nt)
          acc[mt][nt] = __builtin_amdgcn_mfma_f32_16x16x32_bf16(af[mt], bfr[nt], acc[mt][nt], 0, 0, 0);
      __builtin_amdgcn_s_setprio(0);
    }
  }
}

// ---------------------------------------------------------------------------
// QKV projection + bias + RoPE(Q,K) + head-split; V written transposed.
// XCD-cohort remap: the 24 blocks (8 n-tiles x 3 weights) sharing one A-panel
// are consecutive on ONE XCD -> co-resident -> A-panel read from HBM once.
// ---------------------------------------------------------------------------
#define SCQ 0.18033688011112042f   // 0.125 * log2(e)

__global__ __launch_bounds__(256) void gemm_qkv_kernel(
    const u16* __restrict__ xb,
    const u16* __restrict__ wqb, const u16* __restrict__ wkb, const u16* __restrict__ wvb,
    const float* __restrict__ bq, const float* __restrict__ bk, const float* __restrict__ bv,
    const float2* __restrict__ rope,
    u16* __restrict__ Qh, u16* __restrict__ Kh, u16* __restrict__ Vt)
{
  __shared__ u16 sA[128*64];
  __shared__ u16 sB[128*64];

  // bid 0..1535 -> xcd cohort decode
  const int bid = blockIdx.x;
  const int xcd = bid & 7, gg = bid >> 3;      // gg: 0..191
  const int slot = xcd * 192 + gg;             // contiguous per XCD
  const int my   = slot / 24;                  // A-panel (128 tokens) 0..63
  const int rem  = slot % 24;
  const int z    = rem >> 3;                   // weight 0..2
  const int mx   = rem & 7;                    // n-tile 0..7

  const u16*  W    = (z == 0) ? wqb : (z == 1) ? wkb : wvb;
  const float* bias = (z == 0) ? bq  : (z == 1) ? bk  : bv;
  const int m0 = my * 128, n0 = mx * 128;

  f32x4 acc[4][4];
  gemm128_mainloop(xb, W, m0, n0, CMODEL, sA, sB, acc);

  const int tid = threadIdx.x, w = tid >> 6, lane = tid & 63;
  const int ln = lane & 15, g = lane >> 4;
  const int wm = w >> 1, wn = w & 1;

#pragma unroll
  for (int mt = 0; mt < 4; ++mt){
#pragma unroll
    for (int nt = 0; nt < 4; ++nt){
      int o  = n0 + wn*64 + nt*16 + ln;    // output feature 0..1023
      float bb = bias[o];
      int h  = o >> 6;
      int dd = o & 63;
      if (z < 2){
        int j = dd >> 1;
        u16* dst = (z == 0) ? Qh : Kh;
        float qs = (z == 0) ? SCQ : 1.0f;
#pragma unroll
        for (int rr = 0; rr < 4; ++rr){
          int t  = m0 + wm*64 + mt*16 + g*4 + rr;   // global token
          int b  = t >> 11, tt = t & (TSEQ-1);
          float v  = acc[mt][nt][rr] + bb;
          float pv = __shfl_xor(v, 1);              // rope partner (o^1), same row
          float2 cs = rope[tt*32 + j];
          float out = ((o & 1) == 0) ? (v*cs.x - pv*cs.y) : (pv*cs.y + v*cs.x);
          dst[(size_t)((b*NHEAD + h)*TSEQ + tt)*HDIM + dd] = f2bf(out * qs);
        }
      } else {
        int t0 = m0 + wm*64 + mt*16 + g*4;
        int b  = t0 >> 11, tt0 = t0 & (TSEQ-1);
        u16 pk[4];
#pragma unroll
        for (int rr = 0; rr < 4; ++rr) pk[rr] = f2bf(acc[mt][nt][rr] + bb);
        *(ushort4*)&Vt[(size_t)((b*NHEAD + h)*HDIM + dd)*TSEQ + tt0] =
            make_ushort4(pk[0], pk[1], pk[2], pk[3]);
      }
    }
  }
}

// ---------------------------------------------------------------------------
// Flash attention v15 — 8-wave blocks, one 256-row supertile per block;
// balanced pairing: q = bid>>6; s = (q<4) ? 7-q : q-4 (CU pairs sum to 7);
// XCD grouping bh = (bid&7)*8 + ((bid>>3)&7); KVBLK=64 triple-buffered with
// counted vmcnt(2); verified swapped-32x32 wave math.
// ---------------------------------------------------------------------------
__global__ __launch_bounds__(512, 4) void attn_kernel(
    const u16* __restrict__ Qh, const u16* __restrict__ Kh,
    const u16* __restrict__ Vt, u16* __restrict__ yb)
{
  __shared__ u16 sK[3][64*64];
  __shared__ u16 sV[3][64*64];

  const int tid = threadIdx.x, w = tid >> 6, lane = tid & 63;
  const int ln = lane & 31, hi = lane >> 5;

  const int bid = blockIdx.x;                  // 0..511
  const int q8  = bid >> 6;                    // 0..7
  const int s   = (q8 < 4) ? (7 - q8) : (q8 - 4);  // balanced pairing
  const int bh  = (bid & 7) * 8 + ((bid >> 3) & 7);
  const int b   = bh >> 4, h = bh & (NHEAD-1);

  const u16* Qbase = Qh + (size_t)bh * TSEQ * HDIM;
  const u16* Kbase = Kh + (size_t)bh * TSEQ * HDIM;
  const u16* Vbase = Vt + (size_t)bh * HDIM * TSEQ;

  // staging: thread stages chunk tid of K tile and of V tile (8KB each)
  const int cr = tid >> 3, cs = tid & 7;
  const u16* kp = Kbase + (size_t)cr*HDIM + ((cs ^ (cr&7))<<3);
  const u16* vp = Vbase + (size_t)cr*TSEQ + ((cs ^ (cr&7))<<3);
  const unsigned dstw = (unsigned)(w*64)*8;    // wave-uniform LDS base (u16)

  // frag read offsets (u16 units), rows are 64-u16 wide
  const int swz = ln & 7;
  unsigned offd[4];
#pragma unroll
  for (int d = 0; d < 4; ++d) offd[d] = ((unsigned)((2*d + hi) ^ swz)) * 8;
  const unsigned rowl = (unsigned)ln * 64;
  const unsigned rowh = rowl + 32*64;

  const f32x16 zero16 = {0,0,0,0,0,0,0,0,0,0,0,0,0,0,0,0};
  const int wodd = w & 1;

  const int r0  = s*256 + w*32;                // wave's first q-row
  const int jtb = 4*s + 3;                     // supertile's last kv-tile
  const int jtw = 4*s + (w >> 1);              // wave's diagonal kv-tile

  // Q fragments
  bf16x8 qf[4];
#pragma unroll
  for (int ds = 0; ds < 4; ++ds)
    qf[ds] = *(const bf16x8*)&Qbase[(size_t)(r0 + ln)*HDIM + ds*16 + hi*8];

  f32x16 yacc0 = zero16, yacc1 = zero16;
  float m2 = -1e30f, lp = 0.f;

  // prologue: stage tiles 0,1 -> bufs 0,1  (jtb >= 3 always)
  async16(kp,                   sK[0] + dstw);
  async16(vp,                   sV[0] + dstw);
  async16(kp + (size_t)64*HDIM, sK[1] + dstw);
  async16(vp + 64,              sV[1] + dstw);
  asm volatile("s_waitcnt vmcnt(2)" ::: "memory");
  asm volatile("s_barrier" ::: "memory");

#pragma unroll 1
  for (int jt = 0; jt <= jtb; ++jt){
    // stage jt+2 into buf (jt+2)%3
    const bool st2 = (jt + 2 <= jtb);
    if (st2){
      const int nb = (jt + 2) % 3;
      async16(kp + (size_t)(jt+2)*64*HDIM, sK[nb] + dstw);
      async16(vp + (size_t)(jt+2)*64,      sV[nb] + dstw);
    }

    if (jt <= jtw){
      const int cb = jt % 3;
      const u16* sKb = sK[cb];
      const u16* sVb = sV[cb];
      const bool full1 = (jt < jtw) || wodd;

      // ---- QK^T (swapped): p0 = kv rows 0..31, p1 = 32..63 ----
      f32x16 p0 = zero16, p1 = zero16;
      __builtin_amdgcn_s_setprio(1);
#pragma unroll
      for (int ds = 0; ds < 4; ++ds){
        bf16x8 k0 = *(const bf16x8*)&sKb[rowl + offd[ds]];
        p0 = __builtin_amdgcn_mfma_f32_32x32x16_bf16(k0, qf[ds], p0, 0, 0, 0);
      }
      if (full1){
#pragma unroll
        for (int ds = 0; ds < 4; ++ds){
          bf16x8 k1 = *(const bf16x8*)&sKb[rowh + offd[ds]];
          p1 = __builtin_amdgcn_mfma_f32_32x32x16_bf16(k1, qf[ds], p1, 0, 0, 0);
        }
      }
      __builtin_amdgcn_s_setprio(0);

      // ---- causal mask on the wave's diag tile ----
      if (jt == jtw){
#pragma unroll
        for (int r = 0; r < 16; ++r){
          int k0r = (r&3) + 8*(r>>2) + 4*hi;
          bool cut = k0r > ln;
          if (!wodd){ if (cut) p0[r] = -1e30f; }
          else      { if (cut) p1[r] = -1e30f; }
        }
      }

      // ---- lane-local row max ----
      float lm = p0[0];
#pragma unroll
      for (int r = 1; r < 16; ++r) lm = fmaxf(lm, p0[r]);
      if (full1){
#pragma unroll
        for (int r = 0; r < 16; ++r) lm = fmaxf(lm, p1[r]);
      }

      // defer-max
      if (__any(lm - m2 > 8.0f)){
        float lmp = __shfl_xor(lm, 32);
        float mn  = fmaxf(m2, fmaxf(lm, lmp));
        float scl = exp2f(m2 - mn);
        m2 = mn;
        lp *= scl;
#pragma unroll
        for (int r = 0; r < 16; ++r){
          float sr = __shfl(scl, (r&3) + 8*(r>>2) + 4*hi);
          yacc0[r] *= sr; yacc1[r] *= sr;
        }
      }

      // ---- exp + per-lane partial sum ----
      float ts = 0.f;
#pragma unroll
      for (int r = 0; r < 16; ++r){ p0[r] = exp2f(p0[r] - m2); ts += p0[r]; }
      if (full1){
#pragma unroll
        for (int r = 0; r < 16; ++r){ p1[r] = exp2f(p1[r] - m2); ts += p1[r]; }
      }
      lp += ts;

      // ---- pack P into PV A-fragments ----
      bf16x8 pa[4];
      {
        union { unsigned u[4]; bf16x8 v; } f0, f1;
        unsigned A0 = cvtpk(p0[0], p0[1]),  B0 = cvtpk(p0[2], p0[3]);
        unsigned A1 = cvtpk(p0[4], p0[5]),  B1 = cvtpk(p0[6], p0[7]);
        plswap(A0, A1); plswap(B0, B1);
        f0.u[0]=A0; f0.u[1]=B0; f0.u[2]=A1; f0.u[3]=B1;  pa[0]=f0.v;
        unsigned A2 = cvtpk(p0[8], p0[9]),  B2 = cvtpk(p0[10], p0[11]);
        unsigned A3 = cvtpk(p0[12], p0[13]),B3 = cvtpk(p0[14], p0[15]);
        plswap(A2, A3); plswap(B2, B3);
        f1.u[0]=A2; f1.u[1]=B2; f1.u[2]=A3; f1.u[3]=B3;  pa[1]=f1.v;
      }
      if (full1){
        union { unsigned u[4]; bf16x8 v; } f2, f3;
        unsigned A4 = cvtpk(p1[0], p1[1]),  B4 = cvtpk(p1[2], p1[3]);
        unsigned A5 = cvtpk(p1[4], p1[5]),  B5 = cvtpk(p1[6], p1[7]);
        plswap(A4, A5); plswap(B4, B5);
        f2.u[0]=A4; f2.u[1]=B4; f2.u[2]=A5; f2.u[3]=B5;  pa[2]=f2.v;
        unsigned A6 = cvtpk(p1[8], p1[9]),  B6 = cvtpk(p1[10], p1[11]);
        unsigned A7 = cvtpk(p1[12], p1[13]),B7 = cvtpk(p1[14], p1[15]);
        plswap(A6, A7); plswap(B6, B7);
        f3.u[0]=A6; f3.u[1]=B6; f3.u[2]=A7; f3.u[3]=B7;  pa[3]=f3.v;
      }

      // ---- PV ----
      __builtin_amdgcn_s_setprio(1);
#pragma unroll
      for (int st = 0; st < 2; ++st){
        bf16x8 v0 = *(const bf16x8*)&sVb[rowl + offd[st]];
        bf16x8 v1 = *(const bf16x8*)&sVb[rowh + offd[st]];
        yacc0 = __builtin_amdgcn_mfma_f32_32x32x16_bf16(pa[st], v0, yacc0, 0, 0, 0);
        yacc1 = __builtin_amdgcn_mfma_f32_32x32x16_bf16(pa[st], v1, yacc1, 0, 0, 0);
      }
      if (full1){
#pragma unroll
        for (int st = 2; st < 4; ++st){
          bf16x8 v0 = *(const bf16x8*)&sVb[rowl + offd[st]];
          bf16x8 v1 = *(const bf16x8*)&sVb[rowh + offd[st]];
          yacc0 = __builtin_amdgcn_mfma_f32_32x32x16_bf16(pa[st], v0, yacc0, 0, 0, 0);
          yacc1 = __builtin_amdgcn_mfma_f32_32x32x16_bf16(pa[st], v1, yacc1, 0, 0, 0);
        }
      }
      __builtin_amdgcn_s_setprio(0);
    }

    // ledger: ensure stage(jt+1) landed before next iter; never 0 until tail
    if (st2) asm volatile("s_waitcnt vmcnt(2)" ::: "memory");
    else     asm volatile("s_waitcnt vmcnt(0)" ::: "memory");
    asm volatile("s_barrier" ::: "memory");
  }

  // ---- epilogue: full row sum, divide, write [token][C] bf16 ----
  float lpf = lp + __shfl_xor(lp, 32);
  float inv = 1.0f / lpf;
#pragma unroll
  for (int r = 0; r < 16; ++r){
    int q = (r&3) + 8*(r>>2) + 4*hi;
    float ir = __shfl(inv, q);
    int tt = r0 + q;
    size_t rowoff = (size_t)(b*TSEQ + tt)*CMODEL + h*HDIM;
    yb[rowoff + ln]      = f2bf(yacc0[r] * ir);
    yb[rowoff + 32 + ln] = f2bf(yacc1[r] * ir);
  }
}

// ---------------------------------------------------------------------------
// output projection (128x128 BK=64), XCD-cohort remap (8 blocks per A-panel).
// ---------------------------------------------------------------------------
__global__ __launch_bounds__(256) void gemm_proj_kernel(
    const u16* __restrict__ yb, const u16* __restrict__ wpb,
    const float* __restrict__ bp, float* __restrict__ out)
{
  __shared__ u16 sA[128*64];
  __shared__ u16 sB[128*64];

  const int bid = blockIdx.x;                  // 0..511
  const int xcd = bid & 7, gg = bid >> 3;      // gg: 0..63
  const int slot = xcd * 64 + gg;
  const int my   = slot >> 3;                  // A-panel 0..63
  const int mx   = slot & 7;                   // n-tile 0..7
  const int m0 = my * 128, n0 = mx * 128;

  f32x4 acc[4][4];
  gemm128_mainloop(yb, wpb, m0, n0, CMODEL, sA, sB, acc);

  const int tid = threadIdx.x, w = tid >> 6, lane = tid & 63;
  const int ln = lane & 15, g = lane >> 4;
  const int wm = w >> 1, wn = w & 1;
#pragma unroll
  for (int mt = 0; mt < 4; ++mt)
#pragma unroll
    for (int nt = 0; nt < 4; ++nt){
      int o = n0 + wn*64 + nt*16 + ln;
      float bb = bp[o];
#pragma unroll
      for (int rr = 0; rr < 4; ++rr){
        int t = m0 + wm*64 + mt*16 + g*4 + rr;
        out[(size_t)t*CMODEL + o] = acc[mt][nt][rr] + bb;
      }
    }
}

// ---------------------------------------------------------------------------
extern "C" void kernel_launch(void* const* d_in, const int* in_sizes, int n_in,
                              void* d_out, int out_size, void* d_ws, size_t ws_size,
                              hipStream_t stream)
{
  const float* x  = (const float*)d_in[0];
  const float* wq = (const float*)d_in[1];
  const float* bq = (const float*)d_in[2];
  const float* wk = (const float*)d_in[3];
  const float* bk = (const float*)d_in[4];
  const float* wv = (const float*)d_in[5];
  const float* bv = (const float*)d_in[6];
  const float* wp = (const float*)d_in[7];
  const float* bp = (const float*)d_in[8];

  char* ws = (char*)d_ws;
  u16*    xb   = (u16*)   (ws + 0);           // 16 MiB
  u16*    wqb  = (u16*)   (ws + 16777216);    // 2 MiB
  u16*    wkb  = (u16*)   (ws + 18874368);
  u16*    wvb  = (u16*)   (ws + 20971520);
  u16*    wpb  = (u16*)   (ws + 23068672);
  float2* rope = (float2*)(ws + 25165824);    // 512 KiB
  u16*    Qh   = (u16*)   (ws + 25690112);    // 16 MiB  [bh][t][d]
  u16*    Kh   = (u16*)   (ws + 42467328);    // 16 MiB  [bh][t][d]
  u16*    Vt   = (u16*)   (ws + 59244544);    // 16 MiB  [bh][d][t]
  u16*    yb   = (u16*)   (ws + 76021760);    // 16 MiB  [token][C]

  cast_bf16_kernel<<<2048, 256, 0, stream>>>(x,  xb,  MTOK*CMODEL/4);
  cast4_bf16_kernel<<<dim3(256, 4), 256, 0, stream>>>(wq, wk, wv, wp, wqb, wkb, wvb, wpb,
                                                      CMODEL*CMODEL/4);
  rope_table_kernel<<<(TSEQ*(HDIM/2) + 255)/256, 256, 0, stream>>>(rope);

  gemm_qkv_kernel<<<dim3(1536), 256, 0, stream>>>(
      xb, wqb, wkb, wvb, bq, bk, bv, rope, Qh, Kh, Vt);

  attn_kernel<<<dim3(512), 512, 0, stream>>>(Qh, Kh, Vt, yb);

  gemm_proj_kernel<<<dim3(512), 256, 0, stream>>>(yb, wpb, bp, (float*)d_out);
}

// Round 22
// 184.036 us; speedup vs baseline: 1.2512x; 1.0227x over previous
//
#include <hip/hip_runtime.h>

typedef __attribute__((ext_vector_type(8))) __bf16 bf16x8;
typedef __attribute__((ext_vector_type(4))) float f32x4;
typedef __attribute__((ext_vector_type(16))) float f32x16;
typedef unsigned short u16;

// Problem constants
#define TSEQ   2048
#define NB     4
#define NHEAD  16
#define HDIM   64
#define CMODEL 1024
#define MTOK   (NB*TSEQ)          // 8192 tokens

__device__ __forceinline__ u16 f2bf(float x){
  unsigned u = __float_as_uint(x);
  u += 0x7fffu + ((u >> 16) & 1u);          // RNE (no NaN inputs here)
  return (u16)(u >> 16);
}

// pack 2 f32 -> u32 of 2 bf16 (lo in low 16), RNE
__device__ __forceinline__ unsigned cvtpk(float lo, float hi){
  unsigned r;
  asm("v_cvt_pk_bf16_f32 %0, %1, %2" : "=v"(r) : "v"(lo), "v"(hi));
  return r;
}
// v_permlane32_swap: a.lanes[32:63] <-> b.lanes[0:31]
__device__ __forceinline__ void plswap(unsigned &a, unsigned &b){
  asm volatile("v_permlane32_swap_b32 %0, %1" : "+v"(a), "+v"(b));
}

// async global->LDS, 16B per lane. lds_base must be wave-uniform (affine in
// lane with 16B slope); HW writes lane i at base + i*16.
__device__ __forceinline__ void async16(const void* g, const u16* lds_base){
  __builtin_amdgcn_global_load_lds(
      (const __attribute__((address_space(1))) unsigned*)(uintptr_t)g,
      (__attribute__((address_space(3))) unsigned*)(unsigned)(uintptr_t)lds_base,
      16, 0, 0);
}

// ---------------------------------------------------------------------------
// fused prep: one launch does x-cast (blocks 0..2047), weight casts
// (blocks 2048..3071, 256 per weight), rope table (blocks 3072..3327).
// ---------------------------------------------------------------------------
__global__ void prep_kernel(const float* __restrict__ x,
                            const float* __restrict__ wq, const float* __restrict__ wk,
                            const float* __restrict__ wv, const float* __restrict__ wp,
                            u16* __restrict__ xb,
                            u16* __restrict__ wqb, u16* __restrict__ wkb,
                            u16* __restrict__ wvb, u16* __restrict__ wpb,
                            float2* __restrict__ rope)
{
  const int bid = blockIdx.x, tid = threadIdx.x;
  if (bid < 2048){
    // x cast: 2M float4 elements, grid-stride over 2048 blocks (4 iters)
    int i = bid*256 + tid;
    const int n4 = MTOK*CMODEL/4, stride = 2048*256;
#pragma unroll
    for (int k = 0; k < 4; ++k, i += stride){
      float4 v = ((const float4*)x)[i];
      ((ushort4*)xb)[i] = make_ushort4(f2bf(v.x), f2bf(v.y), f2bf(v.z), f2bf(v.w));
    }
    (void)n4;
  } else if (bid < 3072){
    // weight casts: 256 blocks per weight, 256K float4 each (4 iters)
    const int which = (bid - 2048) >> 8;
    const int lb    = (bid - 2048) & 255;
    const float* s = (which==0)?wq:(which==1)?wk:(which==2)?wv:wp;
    u16*         d = (which==0)?wqb:(which==1)?wkb:(which==2)?wvb:wpb;
    int i = lb*256 + tid;
    const int stride = 256*256;
#pragma unroll
    for (int k = 0; k < 4; ++k, i += stride){
      float4 v = ((const float4*)s)[i];
      ((ushort4*)d)[i] = make_ushort4(f2bf(v.x), f2bf(v.y), f2bf(v.z), f2bf(v.w));
    }
  } else {
    // rope table: 65536 entries, 256 blocks x 256 thr
    int i = (bid - 3072)*256 + tid;
    int t = i >> 5, j = i & 31;
    float theta = exp2f(-(float)j * (13.287712379549449f / 32.f));
    float ang = (float)t * theta;
    rope[i] = make_float2(cosf(ang), sinf(ang));
  }
}

// ---------------------------------------------------------------------------
// 128x128 tile GEMM, BK=64, double-staged LDS (32KB -> ~4 blocks/CU).
// ---------------------------------------------------------------------------
__device__ __forceinline__ void gemm128_mainloop(
    const u16* __restrict__ A, const u16* __restrict__ B,
    int m0, int n0, int K, u16* sA, u16* sB, f32x4 acc[4][4])
{
  const int tid = threadIdx.x;
  const int w = tid >> 6, lane = tid & 63;
  const int ln = lane & 15, g = lane >> 4;
  const int wm = w >> 1, wn = w & 1;

  const f32x4 zero = {0.f, 0.f, 0.f, 0.f};
#pragma unroll
  for (int mt = 0; mt < 4; ++mt)
#pragma unroll
    for (int nt = 0; nt < 4; ++nt) acc[mt][nt] = zero;

  for (int k0 = 0; k0 < K; k0 += 64){
    __syncthreads();                       // previous tile fully consumed
#pragma unroll
    for (int i = 0; i < 4; ++i){
      int c = i*256 + tid;                 // chunk id 0..1023
      int r = c >> 3, sl = c & 7;
      int ks = sl ^ (r & 7);               // pre-swizzled source k-chunk
      async16(A + (size_t)(m0 + r)*K + k0 + ks*8, sA + (size_t)(i*256 + w*64)*8);
      async16(B + (size_t)(n0 + r)*K + k0 + ks*8, sB + (size_t)(i*256 + w*64)*8);
    }
    __syncthreads();                       // drains vmcnt -> LDS ready

#pragma unroll
    for (int kk = 0; kk < 2; ++kk){
      bf16x8 af[4], bfr[4];
#pragma unroll
      for (int mt = 0; mt < 4; ++mt){
        int row = wm*64 + mt*16 + ln;
        int sl = (kk*4 + g) ^ (row & 7);
        af[mt] = *(const bf16x8*)&sA[row*64 + sl*8];
      }
#pragma unroll
      for (int nt = 0; nt < 4; ++nt){
        int row = wn*64 + nt*16 + ln;
        int sl = (kk*4 + g) ^ (row & 7);
        bfr[nt] = *(const bf16x8*)&sB[row*64 + sl*8];
      }
      __builtin_amdgcn_s_setprio(1);
#pragma unroll
      for (int mt = 0; mt < 4; ++mt)
#pragma unroll
        for (int nt = 0; nt < 4; ++nt)
          acc[mt][nt] = __builtin_amdgcn_mfma_f32_16x16x32_bf16(af[mt], bfr[nt], acc[mt][nt], 0, 0, 0);
      __builtin_amdgcn_s_setprio(0);
    }
  }
}

// ---------------------------------------------------------------------------
// QKV projection + bias + RoPE(Q,K) + head-split; V written transposed.
// XCD-cohort remap: the 24 blocks (8 n-tiles x 3 weights) sharing one A-panel
// are consecutive on ONE XCD -> co-resident -> A-panel read from HBM once.
// ---------------------------------------------------------------------------
#define SCQ 0.18033688011112042f   // 0.125 * log2(e)

__global__ __launch_bounds__(256) void gemm_qkv_kernel(
    const u16* __restrict__ xb,
    const u16* __restrict__ wqb, const u16* __restrict__ wkb, const u16* __restrict__ wvb,
    const float* __restrict__ bq, const float* __restrict__ bk, const float* __restrict__ bv,
    const float2* __restrict__ rope,
    u16* __restrict__ Qh, u16* __restrict__ Kh, u16* __restrict__ Vt)
{
  __shared__ u16 sA[128*64];
  __shared__ u16 sB[128*64];

  // bid 0..1535 -> xcd cohort decode
  const int bid = blockIdx.x;
  const int xcd = bid & 7, gg = bid >> 3;      // gg: 0..191
  const int slot = xcd * 192 + gg;             // contiguous per XCD
  const int my   = slot / 24;                  // A-panel (128 tokens) 0..63
  const int rem  = slot % 24;
  const int z    = rem >> 3;                   // weight 0..2
  const int mx   = rem & 7;                    // n-tile 0..7

  const u16*  W    = (z == 0) ? wqb : (z == 1) ? wkb : wvb;
  const float* bias = (z == 0) ? bq  : (z == 1) ? bk  : bv;
  const int m0 = my * 128, n0 = mx * 128;

  f32x4 acc[4][4];
  gemm128_mainloop(xb, W, m0, n0, CMODEL, sA, sB, acc);

  const int tid = threadIdx.x, w = tid >> 6, lane = tid & 63;
  const int ln = lane & 15, g = lane >> 4;
  const int wm = w >> 1, wn = w & 1;

#pragma unroll
  for (int mt = 0; mt < 4; ++mt){
#pragma unroll
    for (int nt = 0; nt < 4; ++nt){
      int o  = n0 + wn*64 + nt*16 + ln;    // output feature 0..1023
      float bb = bias[o];
      int h  = o >> 6;
      int dd = o & 63;
      if (z < 2){
        int j = dd >> 1;
        u16* dst = (z == 0) ? Qh : Kh;
        float qs = (z == 0) ? SCQ : 1.0f;
#pragma unroll
        for (int rr = 0; rr < 4; ++rr){
          int t  = m0 + wm*64 + mt*16 + g*4 + rr;   // global token
          int b  = t >> 11, tt = t & (TSEQ-1);
          float v  = acc[mt][nt][rr] + bb;
          float pv = __shfl_xor(v, 1);              // rope partner (o^1), same row
          float2 cs = rope[tt*32 + j];
          float out = ((o & 1) == 0) ? (v*cs.x - pv*cs.y) : (pv*cs.y + v*cs.x);
          dst[(size_t)((b*NHEAD + h)*TSEQ + tt)*HDIM + dd] = f2bf(out * qs);
        }
      } else {
        int t0 = m0 + wm*64 + mt*16 + g*4;
        int b  = t0 >> 11, tt0 = t0 & (TSEQ-1);
        u16 pk[4];
#pragma unroll
        for (int rr = 0; rr < 4; ++rr) pk[rr] = f2bf(acc[mt][nt][rr] + bb);
        *(ushort4*)&Vt[(size_t)((b*NHEAD + h)*HDIM + dd)*TSEQ + tt0] =
            make_ushort4(pk[0], pk[1], pk[2], pk[3]);
      }
    }
  }
}

// ---------------------------------------------------------------------------
// Flash attention v15 — 8-wave blocks, one 256-row supertile per block;
// balanced pairing: q = bid>>6; s = (q<4) ? 7-q : q-4 (CU pairs sum to 7);
// XCD grouping bh = (bid&7)*8 + ((bid>>3)&7); KVBLK=64 triple-buffered with
// counted vmcnt(2); verified swapped-32x32 wave math.
// ---------------------------------------------------------------------------
__global__ __launch_bounds__(512, 4) void attn_kernel(
    const u16* __restrict__ Qh, const u16* __restrict__ Kh,
    const u16* __restrict__ Vt, u16* __restrict__ yb)
{
  __shared__ u16 sK[3][64*64];
  __shared__ u16 sV[3][64*64];

  const int tid = threadIdx.x, w = tid >> 6, lane = tid & 63;
  const int ln = lane & 31, hi = lane >> 5;

  const int bid = blockIdx.x;                  // 0..511
  const int q8  = bid >> 6;                    // 0..7
  const int s   = (q8 < 4) ? (7 - q8) : (q8 - 4);  // balanced pairing
  const int bh  = (bid & 7) * 8 + ((bid >> 3) & 7);
  const int b   = bh >> 4, h = bh & (NHEAD-1);

  const u16* Qbase = Qh + (size_t)bh * TSEQ * HDIM;
  const u16* Kbase = Kh + (size_t)bh * TSEQ * HDIM;
  const u16* Vbase = Vt + (size_t)bh * HDIM * TSEQ;

  // staging: thread stages chunk tid of K tile and of V tile (8KB each)
  const int cr = tid >> 3, cs = tid & 7;
  const u16* kp = Kbase + (size_t)cr*HDIM + ((cs ^ (cr&7))<<3);
  const u16* vp = Vbase + (size_t)cr*TSEQ + ((cs ^ (cr&7))<<3);
  const unsigned dstw = (unsigned)(w*64)*8;    // wave-uniform LDS base (u16)

  // frag read offsets (u16 units), rows are 64-u16 wide
  const int swz = ln & 7;
  unsigned offd[4];
#pragma unroll
  for (int d = 0; d < 4; ++d) offd[d] = ((unsigned)((2*d + hi) ^ swz)) * 8;
  const unsigned rowl = (unsigned)ln * 64;
  const unsigned rowh = rowl + 32*64;

  const f32x16 zero16 = {0,0,0,0,0,0,0,0,0,0,0,0,0,0,0,0};
  const int wodd = w & 1;

  const int r0  = s*256 + w*32;                // wave's first q-row
  const int jtb = 4*s + 3;                     // supertile's last kv-tile
  const int jtw = 4*s + (w >> 1);              // wave's diagonal kv-tile

  // Q fragments
  bf16x8 qf[4];
#pragma unroll
  for (int ds = 0; ds < 4; ++ds)
    qf[ds] = *(const bf16x8*)&Qbase[(size_t)(r0 + ln)*HDIM + ds*16 + hi*8];

  f32x16 yacc0 = zero16, yacc1 = zero16;
  float m2 = -1e30f, lp = 0.f;

  // prologue: stage tiles 0,1 -> bufs 0,1  (jtb >= 3 always)
  async16(kp,                   sK[0] + dstw);
  async16(vp,                   sV[0] + dstw);
  async16(kp + (size_t)64*HDIM, sK[1] + dstw);
  async16(vp + 64,              sV[1] + dstw);
  asm volatile("s_waitcnt vmcnt(2)" ::: "memory");
  asm volatile("s_barrier" ::: "memory");

#pragma unroll 1
  for (int jt = 0; jt <= jtb; ++jt){
    // stage jt+2 into buf (jt+2)%3
    const bool st2 = (jt + 2 <= jtb);
    if (st2){
      const int nb = (jt + 2) % 3;
      async16(kp + (size_t)(jt+2)*64*HDIM, sK[nb] + dstw);
      async16(vp + (size_t)(jt+2)*64,      sV[nb] + dstw);
    }

    if (jt <= jtw){
      const int cb = jt % 3;
      const u16* sKb = sK[cb];
      const u16* sVb = sV[cb];
      const bool full1 = (jt < jtw) || wodd;

      // ---- QK^T (swapped): p0 = kv rows 0..31, p1 = 32..63 ----
      f32x16 p0 = zero16, p1 = zero16;
      __builtin_amdgcn_s_setprio(1);
#pragma unroll
      for (int ds = 0; ds < 4; ++ds){
        bf16x8 k0 = *(const bf16x8*)&sKb[rowl + offd[ds]];
        p0 = __builtin_amdgcn_mfma_f32_32x32x16_bf16(k0, qf[ds], p0, 0, 0, 0);
      }
      if (full1){
#pragma unroll
        for (int ds = 0; ds < 4; ++ds){
          bf16x8 k1 = *(const bf16x8*)&sKb[rowh + offd[ds]];
          p1 = __builtin_amdgcn_mfma_f32_32x32x16_bf16(k1, qf[ds], p1, 0, 0, 0);
        }
      }
      __builtin_amdgcn_s_setprio(0);

      // ---- causal mask on the wave's diag tile ----
      if (jt == jtw){
#pragma unroll
        for (int r = 0; r < 16; ++r){
          int k0r = (r&3) + 8*(r>>2) + 4*hi;
          bool cut = k0r > ln;
          if (!wodd){ if (cut) p0[r] = -1e30f; }
          else      { if (cut) p1[r] = -1e30f; }
        }
      }

      // ---- lane-local row max ----
      float lm = p0[0];
#pragma unroll
      for (int r = 1; r < 16; ++r) lm = fmaxf(lm, p0[r]);
      if (full1){
#pragma unroll
        for (int r = 0; r < 16; ++r) lm = fmaxf(lm, p1[r]);
      }

      // defer-max
      if (__any(lm - m2 > 8.0f)){
        float lmp = __shfl_xor(lm, 32);
        float mn  = fmaxf(m2, fmaxf(lm, lmp));
        float scl = exp2f(m2 - mn);
        m2 = mn;
        lp *= scl;
#pragma unroll
        for (int r = 0; r < 16; ++r){
          float sr = __shfl(scl, (r&3) + 8*(r>>2) + 4*hi);
          yacc0[r] *= sr; yacc1[r] *= sr;
        }
      }

      // ---- exp + per-lane partial sum ----
      float ts = 0.f;
#pragma unroll
      for (int r = 0; r < 16; ++r){ p0[r] = exp2f(p0[r] - m2); ts += p0[r]; }
      if (full1){
#pragma unroll
        for (int r = 0; r < 16; ++r){ p1[r] = exp2f(p1[r] - m2); ts += p1[r]; }
      }
      lp += ts;

      // ---- pack P into PV A-fragments ----
      bf16x8 pa[4];
      {
        union { unsigned u[4]; bf16x8 v; } f0, f1;
        unsigned A0 = cvtpk(p0[0], p0[1]),  B0 = cvtpk(p0[2], p0[3]);
        unsigned A1 = cvtpk(p0[4], p0[5]),  B1 = cvtpk(p0[6], p0[7]);
        plswap(A0, A1); plswap(B0, B1);
        f0.u[0]=A0; f0.u[1]=B0; f0.u[2]=A1; f0.u[3]=B1;  pa[0]=f0.v;
        unsigned A2 = cvtpk(p0[8], p0[9]),  B2 = cvtpk(p0[10], p0[11]);
        unsigned A3 = cvtpk(p0[12], p0[13]),B3 = cvtpk(p0[14], p0[15]);
        plswap(A2, A3); plswap(B2, B3);
        f1.u[0]=A2; f1.u[1]=B2; f1.u[2]=A3; f1.u[3]=B3;  pa[1]=f1.v;
      }
      if (full1){
        union { unsigned u[4]; bf16x8 v; } f2, f3;
        unsigned A4 = cvtpk(p1[0], p1[1]),  B4 = cvtpk(p1[2], p1[3]);
        unsigned A5 = cvtpk(p1[4], p1[5]),  B5 = cvtpk(p1[6], p1[7]);
        plswap(A4, A5); plswap(B4, B5);
        f2.u[0]=A4; f2.u[1]=B4; f2.u[2]=A5; f2.u[3]=B5;  pa[2]=f2.v;
        unsigned A6 = cvtpk(p1[8], p1[9]),  B6 = cvtpk(p1[10], p1[11]);
        unsigned A7 = cvtpk(p1[12], p1[13]),B7 = cvtpk(p1[14], p1[15]);
        plswap(A6, A7); plswap(B6, B7);
        f3.u[0]=A6; f3.u[1]=B6; f3.u[2]=A7; f3.u[3]=B7;  pa[3]=f3.v;
      }

      // ---- PV ----
      __builtin_amdgcn_s_setprio(1);
#pragma unroll
      for (int st = 0; st < 2; ++st){
        bf16x8 v0 = *(const bf16x8*)&sVb[rowl + offd[st]];
        bf16x8 v1 = *(const bf16x8*)&sVb[rowh + offd[st]];
        yacc0 = __builtin_amdgcn_mfma_f32_32x32x16_bf16(pa[st], v0, yacc0, 0, 0, 0);
        yacc1 = __builtin_amdgcn_mfma_f32_32x32x16_bf16(pa[st], v1, yacc1, 0, 0, 0);
      }
      if (full1){
#pragma unroll
        for (int st = 2; st < 4; ++st){
          bf16x8 v0 = *(const bf16x8*)&sVb[rowl + offd[st]];
          bf16x8 v1 = *(const bf16x8*)&sVb[rowh + offd[st]];
          yacc0 = __builtin_amdgcn_mfma_f32_32x32x16_bf16(pa[st], v0, yacc0, 0, 0, 0);
          yacc1 = __builtin_amdgcn_mfma_f32_32x32x16_bf16(pa[st], v1, yacc1, 0, 0, 0);
        }
      }
      __builtin_amdgcn_s_setprio(0);
    }

    // ledger: ensure stage(jt+1) landed before next iter; never 0 until tail
    if (st2) asm volatile("s_waitcnt vmcnt(2)" ::: "memory");
    else     asm volatile("s_waitcnt vmcnt(0)" ::: "memory");
    asm volatile("s_barrier" ::: "memory");
  }

  // ---- epilogue: full row sum, divide, write [token][C] bf16 ----
  float lpf = lp + __shfl_xor(lp, 32);
  float inv = 1.0f / lpf;
#pragma unroll
  for (int r = 0; r < 16; ++r){
    int q = (r&3) + 8*(r>>2) + 4*hi;
    float ir = __shfl(inv, q);
    int tt = r0 + q;
    size_t rowoff = (size_t)(b*TSEQ + tt)*CMODEL + h*HDIM;
    yb[rowoff + ln]      = f2bf(yacc0[r] * ir);
    yb[rowoff + 32 + ln] = f2bf(yacc1[r] * ir);
  }
}

// ---------------------------------------------------------------------------
// output projection (128x128 BK=64), XCD-cohort remap (8 blocks per A-panel).
// ---------------------------------------------------------------------------
__global__ __launch_bounds__(256) void gemm_proj_kernel(
    const u16* __restrict__ yb, const u16* __restrict__ wpb,
    const float* __restrict__ bp, float* __restrict__ out)
{
  __shared__ u16 sA[128*64];
  __shared__ u16 sB[128*64];

  const int bid = blockIdx.x;                  // 0..511
  const int xcd = bid & 7, gg = bid >> 3;      // gg: 0..63
  const int slot = xcd * 64 + gg;
  const int my   = slot >> 3;                  // A-panel 0..63
  const int mx   = slot & 7;                   // n-tile 0..7
  const int m0 = my * 128, n0 = mx * 128;

  f32x4 acc[4][4];
  gemm128_mainloop(yb, wpb, m0, n0, CMODEL, sA, sB, acc);

  const int tid = threadIdx.x, w = tid >> 6, lane = tid & 63;
  const int ln = lane & 15, g = lane >> 4;
  const int wm = w >> 1, wn = w & 1;
#pragma unroll
  for (int mt = 0; mt < 4; ++mt)
#pragma unroll
    for (int nt = 0; nt < 4; ++nt){
      int o = n0 + wn*64 + nt*16 + ln;
      float bb = bp[o];
#pragma unroll
      for (int rr = 0; rr < 4; ++rr){
        int t = m0 + wm*64 + mt*16 + g*4 + rr;
        out[(size_t)t*CMODEL + o] = acc[mt][nt][rr] + bb;
      }
    }
}

// ---------------------------------------------------------------------------
extern "C" void kernel_launch(void* const* d_in, const int* in_sizes, int n_in,
                              void* d_out, int out_size, void* d_ws, size_t ws_size,
                              hipStream_t stream)
{
  const float* x  = (const float*)d_in[0];
  const float* wq = (const float*)d_in[1];
  const float* bq = (const float*)d_in[2];
  const float* wk = (const float*)d_in[3];
  const float* bk = (const float*)d_in[4];
  const float* wv = (const float*)d_in[5];
  const float* bv = (const float*)d_in[6];
  const float* wp = (const float*)d_in[7];
  const float* bp = (const float*)d_in[8];

  char* ws = (char*)d_ws;
  u16*    xb   = (u16*)   (ws + 0);           // 16 MiB
  u16*    wqb  = (u16*)   (ws + 16777216);    // 2 MiB
  u16*    wkb  = (u16*)   (ws + 18874368);
  u16*    wvb  = (u16*)   (ws + 20971520);
  u16*    wpb  = (u16*)   (ws + 23068672);
  float2* rope = (float2*)(ws + 25165824);    // 512 KiB
  u16*    Qh   = (u16*)   (ws + 25690112);    // 16 MiB  [bh][t][d]
  u16*    Kh   = (u16*)   (ws + 42467328);    // 16 MiB  [bh][t][d]
  u16*    Vt   = (u16*)   (ws + 59244544);    // 16 MiB  [bh][d][t]
  u16*    yb   = (u16*)   (ws + 76021760);    // 16 MiB  [token][C]

  prep_kernel<<<dim3(3328), 256, 0, stream>>>(x, wq, wk, wv, wp,
                                              xb, wqb, wkb, wvb, wpb, rope);

  gemm_qkv_kernel<<<dim3(1536), 256, 0, stream>>>(
      xb, wqb, wkb, wvb, bq, bk, bv, rope, Qh, Kh, Vt);

  attn_kernel<<<dim3(512), 512, 0, stream>>>(Qh, Kh, Vt, yb);

  gemm_proj_kernel<<<dim3(512), 256, 0, stream>>>(yb, wpb, bp, (float*)d_out);
}